// Round 1
// baseline (728.990 us; speedup 1.0000x reference)
//
#include <hip/hip_runtime.h>
#include <hip/hip_bf16.h>

// Problem constants
#define BB 128
#define SS 200
#define HH 512
#define EE 256
#define VV 50000
#define KGRU 1280   // E + 2H
#define KOUT 1792   // 3H + E
#define N3H 1536

typedef __bf16 bf16x8 __attribute__((ext_vector_type(8)));
typedef __bf16 bf16x4 __attribute__((ext_vector_type(4)));
typedef float  f32x4  __attribute__((ext_vector_type(4)));

// f32 -> (hi, lo) bf16 split: x ~= hi + lo with error ~2^-18 |x|
__device__ __forceinline__ void split2(float x, __bf16* hi, __bf16* lo) {
    __bf16 h = (__bf16)x;
    *hi = h;
    *lo = (__bf16)(x - (float)h);
}
__device__ __forceinline__ __bf16 lo_of(float x) {
    __bf16 h = (__bf16)x;
    return (__bf16)(x - (float)h);
}

// ---------------- u2 = attn_w[:,512:1536]^T @ v  (1024 outputs, full f32) ----------------
// hidden-projection part of scores is constant over s (softmax-invariant); attn_b likewise.
__global__ __launch_bounds__(256) void u2_kernel(const float* __restrict__ attn_w,
                                                 const float* __restrict__ v,
                                                 float* __restrict__ u2) {
    __shared__ float part[4][64];
    const int tid = threadIdx.x, wave = tid >> 6, lane = tid & 63;
    const int j = blockIdx.x * 64 + lane;
    const int h0 = wave * 128;
    float acc = 0.f;
    #pragma unroll 8
    for (int h = 0; h < 128; h++)
        acc += v[h0 + h] * attn_w[(size_t)(h0 + h) * N3H + HH + j];
    part[wave][lane] = acc;
    __syncthreads();
    if (wave == 0)
        u2[j] = part[0][lane] + part[1][lane] + part[2][lane] + part[3][lane];
}

// ---------------- prep: embedding gather (clamped like JAX) + h0 split ----------------
__global__ __launch_bounds__(256) void prep_kernel(const int* __restrict__ x,
                                                   const float* __restrict__ emb,
                                                   const float* __restrict__ h0,
                                                   __bf16* __restrict__ AgruH, __bf16* __restrict__ AgruL,
                                                   __bf16* __restrict__ AoutH, __bf16* __restrict__ AoutL,
                                                   __bf16* __restrict__ Ah0H,  __bf16* __restrict__ Ah0L) {
    const int b = blockIdx.x, t = threadIdx.x;
    int xi = x[b];
    xi = xi < 0 ? 0 : (xi >= VV ? VV - 1 : xi);   // JAX gather clamps OOB indices
    float val = emb[(size_t)xi * EE + t];
    split2(val, &AoutH[(size_t)b * KOUT + 3 * HH + t], &AoutL[(size_t)b * KOUT + 3 * HH + t]);
    float rv = fmaxf(val, 0.f);
    split2(rv, &AgruH[(size_t)b * KGRU + t], &AgruL[(size_t)b * KGRU + t]);
    float ha = h0[(size_t)b * HH + t];
    float hb = h0[(size_t)b * HH + t + 256];
    split2(ha, &Ah0H[(size_t)b * HH + t],       &Ah0L[(size_t)b * HH + t]);
    split2(hb, &Ah0H[(size_t)b * HH + t + 256], &Ah0L[(size_t)b * HH + t + 256]);
}

// ---------------- scores[b,s] = enc[b,s,:] . u2  (full f32) ----------------
__global__ __launch_bounds__(256) void scores_kernel(const float* __restrict__ enc,
                                                     const float* __restrict__ u2,
                                                     float* __restrict__ scores) {
    __shared__ float u2s[2 * HH];
    const int tid = threadIdx.x, wave = tid >> 6, lane = tid & 63;
    const int b = blockIdx.x >> 2, s0 = (blockIdx.x & 3) * 50;
    ((float4*)u2s)[tid] = ((const float4*)u2)[tid];
    __syncthreads();
    const float* encb = enc + (size_t)b * SS * 2 * HH;
    for (int s = s0 + wave; s < s0 + 50; s += 4) {
        const float4* row = (const float4*)(encb + s * 2 * HH);
        float acc = 0.f;
        #pragma unroll
        for (int i = 0; i < 4; i++) {
            float4 e = row[lane + i * 64];
            float4 u = ((const float4*)u2s)[lane + i * 64];
            acc += e.x * u.x + e.y * u.y + e.z * u.z + e.w * u.w;
        }
        #pragma unroll
        for (int off = 32; off; off >>= 1) acc += __shfl_xor(acc, off);
        if (lane == 0) scores[b * SS + s] = acc;
    }
}

// ---------------- softmax + context (f32), split-write into Agru/Aout ----------------
__global__ __launch_bounds__(256) void ctx_kernel(const float* __restrict__ enc,
                                                  const float* __restrict__ scores,
                                                  __bf16* __restrict__ AgruH, __bf16* __restrict__ AgruL,
                                                  __bf16* __restrict__ AoutH, __bf16* __restrict__ AoutL) {
    __shared__ float sc[SS];
    __shared__ float red[8];
    const int tid = threadIdx.x, wave = tid >> 6, lane = tid & 63;
    const int b = blockIdx.x >> 1, d0 = (blockIdx.x & 1) * 512;

    float vv = (tid < SS) ? scores[b * SS + tid] : -3.4e38f;
    float m = vv;
    #pragma unroll
    for (int off = 32; off; off >>= 1) m = fmaxf(m, __shfl_xor(m, off));
    if (lane == 0) red[wave] = m;
    __syncthreads();
    m = fmaxf(fmaxf(red[0], red[1]), fmaxf(red[2], red[3]));
    float p = (tid < SS) ? __expf(vv - m) : 0.f;
    float ssum = p;
    #pragma unroll
    for (int off = 32; off; off >>= 1) ssum += __shfl_xor(ssum, off);
    if (lane == 0) red[4 + wave] = ssum;
    __syncthreads();
    float tot = red[4] + red[5] + red[6] + red[7];
    if (tid < SS) sc[tid] = p / tot;
    __syncthreads();

    const float* encb = enc + (size_t)b * SS * 2 * HH + d0;
    float a0 = 0.f, a1 = 0.f;
    for (int s = 0; s < SS; s += 4) {
        #pragma unroll
        for (int k = 0; k < 4; k++) {
            float ps = sc[s + k];
            const float* row = encb + (s + k) * 2 * HH;
            a0 += ps * row[tid];
            a1 += ps * row[tid + 256];
        }
    }
    int d = d0 + tid;
    __bf16 h, l;
    split2(a0, &h, &l);
    AoutH[(size_t)b * KOUT + HH + d] = h;  AoutL[(size_t)b * KOUT + HH + d] = l;
    split2(fmaxf(a0, 0.f), &h, &l);
    AgruH[(size_t)b * KGRU + EE + d] = h;  AgruL[(size_t)b * KGRU + EE + d] = l;
    split2(a1, &h, &l);
    AoutH[(size_t)b * KOUT + HH + d + 256] = h;  AoutL[(size_t)b * KOUT + HH + d + 256] = l;
    split2(fmaxf(a1, 0.f), &h, &l);
    AgruH[(size_t)b * KGRU + EE + d + 256] = h;  AgruL[(size_t)b * KGRU + EE + d + 256] = l;
}

// ---------------- merged GRU GEMMs, split-bf16 (3 MFMA): blocks 0..23 gi, 24..47 gh ----------------
__global__ __launch_bounds__(256) void gru_gemms(const __bf16* __restrict__ AgruH, const __bf16* __restrict__ AgruL,
                                                 const float* __restrict__ w_ih,
                                                 const float* __restrict__ b_ih,
                                                 float* __restrict__ gi,
                                                 const __bf16* __restrict__ Ah0H, const __bf16* __restrict__ Ah0L,
                                                 const float* __restrict__ w_hh,
                                                 const float* __restrict__ b_hh,
                                                 float* __restrict__ gh) {
    __shared__ __bf16 AsH[128][40];
    __shared__ __bf16 AsL[128][40];
    __shared__ __bf16 BsH[64][40];
    __shared__ __bf16 BsL[64][40];
    const bool second = blockIdx.x >= 24;
    const __bf16* AH   = second ? Ah0H : AgruH;
    const __bf16* AL   = second ? Ah0L : AgruL;
    const float*  B    = second ? w_hh : w_ih;
    const float*  bias = second ? b_hh : b_ih;
    float*        C    = second ? gh   : gi;
    const int K = second ? HH : KGRU;
    const int n0 = (blockIdx.x - (second ? 24 : 0)) * 64;

    const int tid = threadIdx.x, wave = tid >> 6, lane = tid & 63;
    const int q = lane >> 4, r16 = lane & 15;
    const int am = tid >> 1, ah = tid & 1;

    f32x4 acc[8];
    #pragma unroll
    for (int mt = 0; mt < 8; mt++) acc[mt] = f32x4{0.f, 0.f, 0.f, 0.f};

    for (int kc = 0; kc < K; kc += 32) {
        const uint4* aph = (const uint4*)(AH + (size_t)am * K + kc + ah * 16);
        const uint4* apl = (const uint4*)(AL + (size_t)am * K + kc + ah * 16);
        uint4 h0v = aph[0], h1v = aph[1];
        uint4 l0v = apl[0], l1v = apl[1];
        *(uint4*)(&AsH[am][ah * 16])     = h0v;
        *(uint4*)(&AsH[am][ah * 16 + 8]) = h1v;
        *(uint4*)(&AsL[am][ah * 16])     = l0v;
        *(uint4*)(&AsL[am][ah * 16 + 8]) = l1v;
        #pragma unroll
        for (int j = 0; j < 2; j++) {
            int idx = tid + j * 256;
            int row = idx >> 3, col = (idx & 7) * 4;
            float4 bv = *(const float4*)(B + (size_t)(n0 + row) * K + kc + col);
            bf16x4 ph = { (__bf16)bv.x, (__bf16)bv.y, (__bf16)bv.z, (__bf16)bv.w };
            bf16x4 pl = { lo_of(bv.x), lo_of(bv.y), lo_of(bv.z), lo_of(bv.w) };
            *(bf16x4*)(&BsH[row][col]) = ph;
            *(bf16x4*)(&BsL[row][col]) = pl;
        }
        __syncthreads();
        bf16x8 bh = *(const bf16x8*)(&BsH[wave * 16 + r16][q * 8]);
        bf16x8 bl = *(const bf16x8*)(&BsL[wave * 16 + r16][q * 8]);
        #pragma unroll
        for (int mt = 0; mt < 8; mt++) {
            bf16x8 afh = *(const bf16x8*)(&AsH[mt * 16 + r16][q * 8]);
            bf16x8 afl = *(const bf16x8*)(&AsL[mt * 16 + r16][q * 8]);
            acc[mt] = __builtin_amdgcn_mfma_f32_16x16x32_bf16(afh, bl, acc[mt], 0, 0, 0);
            acc[mt] = __builtin_amdgcn_mfma_f32_16x16x32_bf16(afl, bh, acc[mt], 0, 0, 0);
            acc[mt] = __builtin_amdgcn_mfma_f32_16x16x32_bf16(afh, bh, acc[mt], 0, 0, 0);
        }
        __syncthreads();
    }
    const int n = n0 + wave * 16 + r16;
    float bv = bias[n];
    #pragma unroll
    for (int mt = 0; mt < 8; mt++)
        #pragma unroll
        for (int i = 0; i < 4; i++)
            C[(size_t)(mt * 16 + q * 4 + i) * N3H + n] = acc[mt][i] + bv;
}

// ---------------- GRU gates (full f32), h_new split into Aout ----------------
__global__ __launch_bounds__(256) void gate_kernel(const float* __restrict__ gi,
                                                   const float* __restrict__ gh,
                                                   const float* __restrict__ h0,
                                                   float* __restrict__ hout,
                                                   __bf16* __restrict__ AoutH,
                                                   __bf16* __restrict__ AoutL) {
    int i = blockIdx.x * 256 + threadIdx.x;   // 65536
    int b = i >> 9, h = i & 511;
    const float* gib = gi + (size_t)b * N3H;
    const float* ghb = gh + (size_t)b * N3H;
    float r = 1.f / (1.f + __expf(-(gib[h] + ghb[h])));
    float z = 1.f / (1.f + __expf(-(gib[HH + h] + ghb[HH + h])));
    float n = tanhf(gib[2 * HH + h] + r * ghb[2 * HH + h]);
    float hnew = (1.f - z) * n + z * h0[i];
    hout[i] = hnew;
    split2(hnew, &AoutH[(size_t)b * KOUT + h], &AoutL[(size_t)b * KOUT + h]);
}

// ---------------- logits GEMM: 128x128 tile, BK=32, split-bf16 (3 MFMA per product) ----------------
__global__ __launch_bounds__(256, 3) void gemm128(const __bf16* __restrict__ AHp,
                                                  const __bf16* __restrict__ ALp,
                                                  const float* __restrict__ B,
                                                  const float* __restrict__ bias,
                                                  float* __restrict__ C,
                                                  int N, int K) {
    __shared__ __bf16 AsH[128][40];
    __shared__ __bf16 AsL[128][40];
    __shared__ __bf16 BsH[128][40];
    __shared__ __bf16 BsL[128][40];
    const int tid = threadIdx.x, wave = tid >> 6, lane = tid & 63;
    const int q = lane >> 4, r16 = lane & 15;
    const int n0 = blockIdx.x * 128;
    const int row = tid >> 1, half = tid & 1;

    f32x4 acc[8][2];
    #pragma unroll
    for (int mt = 0; mt < 8; mt++) {
        acc[mt][0] = f32x4{0.f, 0.f, 0.f, 0.f};
        acc[mt][1] = f32x4{0.f, 0.f, 0.f, 0.f};
    }

    const bool brow_ok = (n0 + row) < N;
    for (int kc = 0; kc < K; kc += 32) {
        const uint4* aph = (const uint4*)(AHp + (size_t)row * K + kc + half * 16);
        const uint4* apl = (const uint4*)(ALp + (size_t)row * K + kc + half * 16);
        uint4 ah0 = aph[0], ah1 = aph[1];
        uint4 al0 = apl[0], al1 = apl[1];
        float4 bv[4];
        const float* bp = B + (size_t)(n0 + row) * K + kc + half * 16;
        #pragma unroll
        for (int i = 0; i < 4; i++)
            bv[i] = brow_ok ? *(const float4*)(bp + i * 4) : make_float4(0.f, 0.f, 0.f, 0.f);
        *(uint4*)(&AsH[row][half * 16])     = ah0;
        *(uint4*)(&AsH[row][half * 16 + 8]) = ah1;
        *(uint4*)(&AsL[row][half * 16])     = al0;
        *(uint4*)(&AsL[row][half * 16 + 8]) = al1;
        #pragma unroll
        for (int i = 0; i < 4; i++) {
            bf16x4 ph = { (__bf16)bv[i].x, (__bf16)bv[i].y, (__bf16)bv[i].z, (__bf16)bv[i].w };
            bf16x4 pl = { lo_of(bv[i].x), lo_of(bv[i].y), lo_of(bv[i].z), lo_of(bv[i].w) };
            *(bf16x4*)(&BsH[row][half * 16 + i * 4]) = ph;
            *(bf16x4*)(&BsL[row][half * 16 + i * 4]) = pl;
        }
        __syncthreads();
        bf16x8 bh0 = *(const bf16x8*)(&BsH[wave * 32 + r16][q * 8]);
        bf16x8 bh1 = *(const bf16x8*)(&BsH[wave * 32 + 16 + r16][q * 8]);
        bf16x8 bl0 = *(const bf16x8*)(&BsL[wave * 32 + r16][q * 8]);
        bf16x8 bl1 = *(const bf16x8*)(&BsL[wave * 32 + 16 + r16][q * 8]);
        #pragma unroll
        for (int mt = 0; mt < 8; mt++) {
            bf16x8 afh = *(const bf16x8*)(&AsH[mt * 16 + r16][q * 8]);
            bf16x8 afl = *(const bf16x8*)(&AsL[mt * 16 + r16][q * 8]);
            acc[mt][0] = __builtin_amdgcn_mfma_f32_16x16x32_bf16(afh, bl0, acc[mt][0], 0, 0, 0);
            acc[mt][0] = __builtin_amdgcn_mfma_f32_16x16x32_bf16(afl, bh0, acc[mt][0], 0, 0, 0);
            acc[mt][0] = __builtin_amdgcn_mfma_f32_16x16x32_bf16(afh, bh0, acc[mt][0], 0, 0, 0);
            acc[mt][1] = __builtin_amdgcn_mfma_f32_16x16x32_bf16(afh, bl1, acc[mt][1], 0, 0, 0);
            acc[mt][1] = __builtin_amdgcn_mfma_f32_16x16x32_bf16(afl, bh1, acc[mt][1], 0, 0, 0);
            acc[mt][1] = __builtin_amdgcn_mfma_f32_16x16x32_bf16(afh, bh1, acc[mt][1], 0, 0, 0);
        }
        __syncthreads();
    }

    #pragma unroll
    for (int j = 0; j < 2; j++) {
        int n = n0 + wave * 32 + j * 16 + r16;
        if (n < N) {
            float bvv = bias[n];
            #pragma unroll
            for (int mt = 0; mt < 8; mt++)
                #pragma unroll
                for (int i = 0; i < 4; i++)
                    C[(size_t)(mt * 16 + q * 4 + i) * N + n] = acc[mt][j][i] + bvv;
        }
    }
}

extern "C" void kernel_launch(void* const* d_in, const int* in_sizes, int n_in,
                              void* d_out, int out_size, void* d_ws, size_t ws_size,
                              hipStream_t stream) {
    const int*   x      = (const int*)  d_in[0];
    const float* hidden = (const float*)d_in[1];
    const float* enc    = (const float*)d_in[2];
    const float* emb    = (const float*)d_in[3];
    const float* attn_w = (const float*)d_in[4];
    // d_in[5] = attn_b (softmax-invariant: adds attn_b.v, constant over s — exact for any values)
    const float* v      = (const float*)d_in[6];
    const float* w_ih   = (const float*)d_in[7];
    const float* w_hh   = (const float*)d_in[8];
    const float* b_ih   = (const float*)d_in[9];
    const float* b_hh   = (const float*)d_in[10];
    const float* out_w  = (const float*)d_in[11];
    const float* out_b  = (const float*)d_in[12];

    float* out = (float*)d_out;
    float* logits = out;                       // [128, 50000]
    float* hnew_out = out + (size_t)BB * VV;   // [1, 128, 512]

    char* ws = (char*)d_ws;
    float*  u2      = (float*) (ws + 0);          // 1024 f32
    float*  scores  = (float*) (ws + 4096);       // 128*200 f32
    float*  gi      = (float*) (ws + 106496);     // 128*1536 f32
    float*  gh      = (float*) (ws + 892928);     // 128*1536 f32
    __bf16* AgruH   = (__bf16*)(ws + 1679360);    // 128*1280 bf16
    __bf16* AgruL   = (__bf16*)(ws + 2007040);    // 128*1280 bf16
    __bf16* Ah0H    = (__bf16*)(ws + 2334720);    // 128*512  bf16
    __bf16* Ah0L    = (__bf16*)(ws + 2465792);    // 128*512  bf16
    __bf16* AoutH   = (__bf16*)(ws + 2596864);    // 128*1792 bf16
    __bf16* AoutL   = (__bf16*)(ws + 3055616);    // 128*1792 bf16 (ends 3514368)

    u2_kernel<<<16, 256, 0, stream>>>(attn_w, v, u2);
    prep_kernel<<<BB, 256, 0, stream>>>(x, emb, hidden, AgruH, AgruL, AoutH, AoutL, Ah0H, Ah0L);
    scores_kernel<<<BB * 4, 256, 0, stream>>>(enc, u2, scores);
    ctx_kernel<<<BB * 2, 256, 0, stream>>>(enc, scores, AgruH, AgruL, AoutH, AoutL);
    gru_gemms<<<48, 256, 0, stream>>>(AgruH, AgruL, w_ih, b_ih, gi, Ah0H, Ah0L, w_hh, b_hh, gh);
    gate_kernel<<<BB * HH / 256, 256, 0, stream>>>(gi, gh, hidden, hnew_out, AoutH, AoutL);
    gemm128<<<(VV + 127) / 128, 256, 0, stream>>>(AoutH, AoutL, out_w, out_b, logits, VV, KOUT);
}